// Round 8
// baseline (628.473 us; speedup 1.0000x reference)
//
#include <hip/hip_runtime.h>

#define RESO 256
#define NCH 27
#define PTS_PER_BLK 32
#define ITEMS (PTS_PER_BLK * 28)   // 896 work items: 32 points x (1 density + 27 SH)
#define NBUCKET 32768              // (x>>3, y>>3, z>>3) -> 32^3 coarse cells

// ---------------- sort pipeline ----------------

__global__ __launch_bounds__(256) void key_hist_kernel(
    const float* __restrict__ pts, int* __restrict__ keys,
    int* __restrict__ hist, int n)
{
    const int i = blockIdx.x * blockDim.x + threadIdx.x;
    if (i >= n) return;
    const float px = pts[3*i+0], py = pts[3*i+1], pz = pts[3*i+2];
    const int ix = (int)fminf(fmaxf(px*128.0f + 127.5f, 0.0f), 255.0f);
    const int iy = (int)fminf(fmaxf(py*128.0f + 127.5f, 0.0f), 255.0f);
    const int iz = (int)fminf(fmaxf(pz*128.0f + 127.5f, 0.0f), 255.0f);
    const int key = ((ix >> 3) << 10) | ((iy >> 3) << 5) | (iz >> 3);
    keys[i] = key;
    atomicAdd(&hist[key], 1);
}

__global__ __launch_bounds__(1024) void scan_hist_kernel(
    const int* __restrict__ hist, int* __restrict__ offs)
{
    __shared__ int part[1024];
    const int t = threadIdx.x;
    const int base = t * 32;
    int v[32];
    int s = 0;
    #pragma unroll
    for (int k = 0; k < 32; ++k) { v[k] = hist[base + k]; s += v[k]; }
    part[t] = s;
    __syncthreads();
    // Hillis-Steele inclusive scan over 1024 partials
    for (int off = 1; off < 1024; off <<= 1) {
        const int x = (t >= off) ? part[t - off] : 0;
        __syncthreads();
        part[t] += x;
        __syncthreads();
    }
    int run = part[t] - s;   // exclusive prefix for this thread's chunk
    #pragma unroll
    for (int k = 0; k < 32; ++k) { offs[base + k] = run; run += v[k]; }
}

__global__ __launch_bounds__(256) void scatter_kernel(
    const float* __restrict__ pts, const int* __restrict__ keys,
    int* __restrict__ offs, int* __restrict__ perm,
    float* __restrict__ spts, int n)
{
    const int i = blockIdx.x * blockDim.x + threadIdx.x;
    if (i >= n) return;
    const int key = keys[i];
    const int pos = atomicAdd(&offs[key], 1);
    perm[pos] = i;
    spts[3*pos+0] = pts[3*i+0];
    spts[3*pos+1] = pts[3*i+1];
    spts[3*pos+2] = pts[3*i+2];
}

// ---------------- sampling kernel (sorted order, scatter writes) ----------------

__global__ __launch_bounds__(256) void sg_sample_sorted_kernel(
    const float* __restrict__ spts,
    const int*   __restrict__ perm,
    const float* __restrict__ dens,
    const float* __restrict__ sh,
    const int*   __restrict__ links,
    float* __restrict__ out_d,
    float* __restrict__ out_sh,
    int n)
{
    __shared__ float s_w[PTS_PER_BLK][8];
    __shared__ int   s_addr[PTS_PER_BLK][8];
    __shared__ float s_wd[PTS_PER_BLK][8];
    __shared__ int   s_orig[PTS_PER_BLK];

    const int tid = threadIdx.x;
    const int pl  = tid >> 3;
    const int c   = tid & 7;
    const int g   = blockIdx.x * PTS_PER_BLK + pl;   // sorted index

    if (g < n) {
        const float px = spts[3*g+0];
        const float py = spts[3*g+1];
        const float pz = spts[3*g+2];

        const float posx = fminf(fmaxf(px*128.0f + 127.5f, 0.0f), 255.0f);
        const float posy = fminf(fmaxf(py*128.0f + 127.5f, 0.0f), 255.0f);
        const float posz = fminf(fmaxf(pz*128.0f + 127.5f, 0.0f), 255.0f);
        const float lxf = fminf(floorf(posx), 254.0f);
        const float lyf = fminf(floorf(posy), 254.0f);
        const float lzf = fminf(floorf(posz), 254.0f);
        const float tx = posx - lxf;
        const float ty = posy - lyf;
        const float tz = posz - lzf;
        const int base = ((int)lxf << 16) | ((int)lyf << 8) | (int)lzf;
        const int off  = ((c & 4) << 14) + ((c & 2) << 7) + (c & 1);

        const int lnk = links[base + off];

        const float wx = (c & 4) ? tx : 1.0f - tx;
        const float wy = (c & 2) ? ty : 1.0f - ty;
        const float wz = (c & 1) ? tz : 1.0f - tz;
        const float w  = (wx * wy) * wz;

        const int   safe = (lnk >= 0) ? lnk : 0;
        const float wv   = (lnk >= 0) ? w : 0.0f;
        s_w[pl][c]    = wv;
        s_addr[pl][c] = safe * NCH;
        s_wd[pl][c]   = wv * dens[safe];
        s_orig[pl]    = perm[g];     // all 8 lanes write same value
    } else {
        s_w[pl][c]    = 0.0f;
        s_addr[pl][c] = 0;
        s_wd[pl][c]   = 0.0f;
        s_orig[pl]    = 0;
    }
    __syncthreads();

    const int base_pt = blockIdx.x * PTS_PER_BLK;

    float vals[4][8];
    int   pp[4], jj[4];

    #pragma unroll
    for (int u = 0; u < 4; ++u) {
        const int item = tid + u * 256;
        const int it   = (item < ITEMS) ? item : 0;
        const int p = it / 28;
        const int j = it - p * 28;
        pp[u] = p; jj[u] = j;
        const int q = (j == 0) ? 0 : j - 1;
        #pragma unroll
        for (int cc = 0; cc < 8; ++cc) {
            vals[u][cc] = sh[s_addr[p][cc] + q];
        }
    }

    #pragma unroll
    for (int u = 0; u < 4; ++u) {
        const int item = tid + u * 256;
        if (item >= ITEMS) continue;
        const int p = pp[u], j = jj[u];
        if (base_pt + p >= n) continue;
        const int orig = s_orig[p];
        if (j == 0) {
            float a = 0.0f;
            #pragma unroll
            for (int cc = 0; cc < 8; ++cc) a += s_wd[p][cc];
            out_d[orig] = a;
        } else {
            float acc0 = 0.0f, acc1 = 0.0f;
            #pragma unroll
            for (int cc = 0; cc < 8; cc += 2) {
                acc0 += s_w[p][cc]     * vals[u][cc];
                acc1 += s_w[p][cc + 1] * vals[u][cc + 1];
            }
            out_sh[orig * NCH + (j - 1)] = acc0 + acc1;
        }
    }
}

// ---------------- fallback (R7 kernel, unsorted) ----------------

__global__ __launch_bounds__(256) void sg_sample_kernel(
    const float* __restrict__ points,
    const float* __restrict__ dens,
    const float* __restrict__ sh,
    const int*   __restrict__ links,
    float* __restrict__ out_d,
    float* __restrict__ out_sh,
    int n)
{
    __shared__ float s_w[PTS_PER_BLK][8];
    __shared__ int   s_addr[PTS_PER_BLK][8];
    __shared__ float s_wd[PTS_PER_BLK][8];

    const int tid = threadIdx.x;
    const int pl  = tid >> 3;
    const int c   = tid & 7;
    const int pg  = blockIdx.x * PTS_PER_BLK + pl;

    if (pg < n) {
        const float px = points[3*pg+0];
        const float py = points[3*pg+1];
        const float pz = points[3*pg+2];
        const float posx = fminf(fmaxf(px*128.0f + 127.5f, 0.0f), 255.0f);
        const float posy = fminf(fmaxf(py*128.0f + 127.5f, 0.0f), 255.0f);
        const float posz = fminf(fmaxf(pz*128.0f + 127.5f, 0.0f), 255.0f);
        const float lxf = fminf(floorf(posx), 254.0f);
        const float lyf = fminf(floorf(posy), 254.0f);
        const float lzf = fminf(floorf(posz), 254.0f);
        const float tx = posx - lxf, ty = posy - lyf, tz = posz - lzf;
        const int base = ((int)lxf << 16) | ((int)lyf << 8) | (int)lzf;
        const int off  = ((c & 4) << 14) + ((c & 2) << 7) + (c & 1);
        const int lnk = links[base + off];
        const float wx = (c & 4) ? tx : 1.0f - tx;
        const float wy = (c & 2) ? ty : 1.0f - ty;
        const float wz = (c & 1) ? tz : 1.0f - tz;
        const float w  = (wx * wy) * wz;
        const int   safe = (lnk >= 0) ? lnk : 0;
        const float wv   = (lnk >= 0) ? w : 0.0f;
        s_w[pl][c]    = wv;
        s_addr[pl][c] = safe * NCH;
        s_wd[pl][c]   = wv * dens[safe];
    } else {
        s_w[pl][c] = 0.0f; s_addr[pl][c] = 0; s_wd[pl][c] = 0.0f;
    }
    __syncthreads();

    const int base_pt = blockIdx.x * PTS_PER_BLK;
    float vals[4][8];
    int   pp[4], jj[4];

    #pragma unroll
    for (int u = 0; u < 4; ++u) {
        const int item = tid + u * 256;
        const int it   = (item < ITEMS) ? item : 0;
        const int p = it / 28;
        const int j = it - p * 28;
        pp[u] = p; jj[u] = j;
        const int q = (j == 0) ? 0 : j - 1;
        #pragma unroll
        for (int cc = 0; cc < 8; ++cc) vals[u][cc] = sh[s_addr[p][cc] + q];
    }

    #pragma unroll
    for (int u = 0; u < 4; ++u) {
        const int item = tid + u * 256;
        if (item >= ITEMS) continue;
        const int p = pp[u], j = jj[u];
        const int pg2 = base_pt + p;
        if (pg2 >= n) continue;
        if (j == 0) {
            float a = 0.0f;
            #pragma unroll
            for (int cc = 0; cc < 8; ++cc) a += s_wd[p][cc];
            out_d[pg2] = a;
        } else {
            float acc0 = 0.0f, acc1 = 0.0f;
            #pragma unroll
            for (int cc = 0; cc < 8; cc += 2) {
                acc0 += s_w[p][cc]     * vals[u][cc];
                acc1 += s_w[p][cc + 1] * vals[u][cc + 1];
            }
            out_sh[pg2 * NCH + (j - 1)] = acc0 + acc1;
        }
    }
}

// ---------------- launch ----------------

extern "C" void kernel_launch(void* const* d_in, const int* in_sizes, int n_in,
                              void* d_out, int out_size, void* d_ws, size_t ws_size,
                              hipStream_t stream) {
    const float* points = (const float*)d_in[0];
    const float* dens   = (const float*)d_in[1];
    const float* sh     = (const float*)d_in[2];
    const int*   links  = (const int*)d_in[3];
    const int n = in_sizes[0] / 3;

    float* out_d  = (float*)d_out;
    float* out_sh = out_d + n;

    // ws layout: hist[32768] | offs[32768] | keys[n] | perm[n] | spts[3n]
    const size_t histB = (size_t)NBUCKET * 4;
    const size_t need  = 2 * histB + (size_t)n * 4 * 2 + (size_t)n * 12;

    if (ws_size >= need) {
        char* ws = (char*)d_ws;
        int*   hist = (int*)ws;
        int*   offs = (int*)(ws + histB);
        int*   keys = (int*)(ws + 2 * histB);
        int*   perm = (int*)(ws + 2 * histB + (size_t)n * 4);
        float* spts = (float*)(ws + 2 * histB + (size_t)n * 8);

        hipMemsetAsync(hist, 0, histB, stream);

        const int gridN = (n + 255) / 256;
        hipLaunchKernelGGL(key_hist_kernel, dim3(gridN), dim3(256), 0, stream,
                           points, keys, hist, n);
        hipLaunchKernelGGL(scan_hist_kernel, dim3(1), dim3(1024), 0, stream,
                           hist, offs);
        hipLaunchKernelGGL(scatter_kernel, dim3(gridN), dim3(256), 0, stream,
                           points, keys, offs, perm, spts, n);
        const int gridS = (n + PTS_PER_BLK - 1) / PTS_PER_BLK;
        hipLaunchKernelGGL(sg_sample_sorted_kernel, dim3(gridS), dim3(256), 0, stream,
                           spts, perm, dens, sh, links, out_d, out_sh, n);
    } else {
        const int gridS = (n + PTS_PER_BLK - 1) / PTS_PER_BLK;
        hipLaunchKernelGGL(sg_sample_kernel, dim3(gridS), dim3(256), 0, stream,
                           points, dens, sh, links, out_d, out_sh, n);
    }
}

// Round 9
// 471.320 us; speedup vs baseline: 1.3334x; 1.3334x over previous
//
#include <hip/hip_runtime.h>

#define RESO 256
#define NCH 27
#define PTS_PER_BLK 32

__global__ __launch_bounds__(256) void sg_sample_kernel(
    const float* __restrict__ points,
    const float* __restrict__ dens,
    const float* __restrict__ sh,
    const int*   __restrict__ links,
    float* __restrict__ out_d,
    float* __restrict__ out_sh,
    int n)
{
    __shared__ float s_w[PTS_PER_BLK][8];     // trilinear weight (0 if invalid corner)
    __shared__ int   s_addr[PTS_PER_BLK][8];  // lnk*27 (0 if invalid -> row 0, harmless)
    __shared__ float s_wd[PTS_PER_BLK][8];    // w * density (0 if invalid)

    const int tid = threadIdx.x;
    const int pl  = tid >> 3;   // local point 0..31
    const int c   = tid & 7;    // corner 0..7 (dx*4+dy*2+dz)
    const int pg  = blockIdx.x * PTS_PER_BLK + pl;

    if (pg < n) {
        const float px = points[3*pg+0];
        const float py = points[3*pg+1];
        const float pz = points[3*pg+2];

        // pos = clip(p*128 + 127.5, 0, 255); l = clip(floor(pos), 0, 254); t = pos - l
        const float posx = fminf(fmaxf(px*128.0f + 127.5f, 0.0f), 255.0f);
        const float posy = fminf(fmaxf(py*128.0f + 127.5f, 0.0f), 255.0f);
        const float posz = fminf(fmaxf(pz*128.0f + 127.5f, 0.0f), 255.0f);
        const float lxf = fminf(floorf(posx), 254.0f);
        const float lyf = fminf(floorf(posy), 254.0f);
        const float lzf = fminf(floorf(posz), 254.0f);
        const float tx = posx - lxf;
        const float ty = posy - lyf;
        const float tz = posz - lzf;
        const int base = ((int)lxf << 16) | ((int)lyf << 8) | (int)lzf;
        const int off  = ((c & 4) << 14) + ((c & 2) << 7) + (c & 1);

        const int lnk = links[base + off];

        const float wx = (c & 4) ? tx : 1.0f - tx;
        const float wy = (c & 2) ? ty : 1.0f - ty;
        const float wz = (c & 1) ? tz : 1.0f - tz;
        const float w  = (wx * wy) * wz;

        const int   safe = (lnk >= 0) ? lnk : 0;
        const float wv   = (lnk >= 0) ? w : 0.0f;
        s_w[pl][c]    = wv;
        s_addr[pl][c] = safe * NCH;
        s_wd[pl][c]   = wv * dens[safe];
    } else {
        s_w[pl][c]    = 0.0f;
        s_addr[pl][c] = 0;
        s_wd[pl][c]   = 0.0f;
    }
    __syncthreads();

    const int base_pt = blockIdx.x * PTS_PER_BLK;

    // Phase 2: one item per thread.
    //   tid <  224 : (point p = tid/7, quad q = tid%7) -> 4 consecutive SH
    //                channels via one 16B load per corner (dwordx4, 4B-aligned
    //                is legal on CDNA). Quad 6 loads ch 23..26, stores 24..26.
    //   tid >= 224 : density for point p = tid-224.
    if (tid < 224) {
        const int p   = tid / 7;
        const int q   = tid - p * 7;
        const int pg2 = base_pt + p;
        const int ch0 = (q < 6) ? (4 * q) : 23;

        float v[8][4];
        #pragma unroll
        for (int cc = 0; cc < 8; ++cc) {
            __builtin_memcpy(&v[cc][0], sh + s_addr[p][cc] + ch0, 16);
        }

        float acc[4] = {0.0f, 0.0f, 0.0f, 0.0f};
        #pragma unroll
        for (int cc = 0; cc < 8; ++cc) {
            const float w = s_w[p][cc];
            #pragma unroll
            for (int k = 0; k < 4; ++k) acc[k] += w * v[cc][k];
        }

        if (pg2 < n) {
            float* o = out_sh + (size_t)pg2 * NCH + ch0;
            if (q < 6) {
                __builtin_memcpy(o, acc, 16);
            } else {
                o[1] = acc[1];
                o[2] = acc[2];
                o[3] = acc[3];
            }
        }
    } else {
        const int p   = tid - 224;
        const int pg2 = base_pt + p;
        if (pg2 < n) {
            float a = 0.0f;
            #pragma unroll
            for (int cc = 0; cc < 8; ++cc) a += s_wd[p][cc];
            out_d[pg2] = a;
        }
    }
}

extern "C" void kernel_launch(void* const* d_in, const int* in_sizes, int n_in,
                              void* d_out, int out_size, void* d_ws, size_t ws_size,
                              hipStream_t stream) {
    const float* points = (const float*)d_in[0];
    const float* dens   = (const float*)d_in[1];
    const float* sh     = (const float*)d_in[2];
    const int*   links  = (const int*)d_in[3];
    const int n = in_sizes[0] / 3;

    float* out_d  = (float*)d_out;
    float* out_sh = out_d + n;

    const int grid = (n + PTS_PER_BLK - 1) / PTS_PER_BLK;
    hipLaunchKernelGGL(sg_sample_kernel, dim3(grid), dim3(256), 0, stream,
                       points, dens, sh, links, out_d, out_sh, n);
}

// Round 10
// 452.084 us; speedup vs baseline: 1.3902x; 1.0425x over previous
//
#include <hip/hip_runtime.h>

#define RESO 256
#define NCH 27
#define PTS_PER_BLK 32
#define ITEMS (PTS_PER_BLK * 28)   // 896 work items: 32 points x (1 density + 27 SH)

__global__ __launch_bounds__(256) void sg_sample_kernel(
    const float* __restrict__ points,
    const float* __restrict__ dens,
    const float* __restrict__ sh,
    const int*   __restrict__ links,
    float* __restrict__ out_d,
    float* __restrict__ out_sh,
    int n)
{
    __shared__ float s_w[PTS_PER_BLK][8];     // trilinear weight (0 if invalid corner)
    __shared__ int   s_addr[PTS_PER_BLK][8];  // lnk*27 (0 if invalid -> row 0, harmless)
    __shared__ float s_wd[PTS_PER_BLK][8];    // w * density (0 if invalid)

    const int tid = threadIdx.x;
    const int pl  = tid >> 3;   // local point 0..31
    const int c   = tid & 7;    // corner 0..7 (dx*4+dy*2+dz)
    const int pg  = blockIdx.x * PTS_PER_BLK + pl;

    if (pg < n) {
        const float px = points[3*pg+0];
        const float py = points[3*pg+1];
        const float pz = points[3*pg+2];

        // pos = clip(p*128 + 127.5, 0, 255); l = clip(floor(pos), 0, 254); t = pos - l
        const float posx = fminf(fmaxf(px*128.0f + 127.5f, 0.0f), 255.0f);
        const float posy = fminf(fmaxf(py*128.0f + 127.5f, 0.0f), 255.0f);
        const float posz = fminf(fmaxf(pz*128.0f + 127.5f, 0.0f), 255.0f);
        const float lxf = fminf(floorf(posx), 254.0f);
        const float lyf = fminf(floorf(posy), 254.0f);
        const float lzf = fminf(floorf(posz), 254.0f);
        const float tx = posx - lxf;
        const float ty = posy - lyf;
        const float tz = posz - lzf;
        const int base = ((int)lxf << 16) | ((int)lyf << 8) | (int)lzf;
        const int off  = ((c & 4) << 14) + ((c & 2) << 7) + (c & 1);

        const int lnk = links[base + off];

        const float wx = (c & 4) ? tx : 1.0f - tx;
        const float wy = (c & 2) ? ty : 1.0f - ty;
        const float wz = (c & 1) ? tz : 1.0f - tz;
        const float w  = (wx * wy) * wz;

        const int   safe = (lnk >= 0) ? lnk : 0;
        const float wv   = (lnk >= 0) ? w : 0.0f;
        s_w[pl][c]    = wv;
        s_addr[pl][c] = safe * NCH;
        s_wd[pl][c]   = wv * dens[safe];
    } else {
        s_w[pl][c]    = 0.0f;
        s_addr[pl][c] = 0;
        s_wd[pl][c]   = 0.0f;
    }
    __syncthreads();

    const int base_pt = blockIdx.x * PTS_PER_BLK;

    // Phase 2: 896 items over 256 threads, 4 items/thread. ALL 32 corner loads
    // issued in ONE branchless burst (invalid corners read row 0 and get
    // multiplied by w=0), then reduce + store. Maximizes in-flight misses.
    float vals[4][8];
    int   pp[4], jj[4];

    #pragma unroll
    for (int u = 0; u < 4; ++u) {
        const int item = tid + u * 256;
        const int it   = (item < ITEMS) ? item : 0;   // dead items alias item 0 (cached)
        const int p = it / 28;
        const int j = it - p * 28;
        pp[u] = p; jj[u] = j;
        const int q = (j == 0) ? 0 : j - 1;           // density items load q=0 (L1 hit)
        #pragma unroll
        for (int cc = 0; cc < 8; ++cc) {
            vals[u][cc] = sh[s_addr[p][cc] + q];
        }
    }

    #pragma unroll
    for (int u = 0; u < 4; ++u) {
        const int item = tid + u * 256;
        if (item >= ITEMS) continue;
        const int p = pp[u], j = jj[u];
        const int pg2 = base_pt + p;
        if (pg2 >= n) continue;
        if (j == 0) {
            float a = 0.0f;
            #pragma unroll
            for (int cc = 0; cc < 8; ++cc) a += s_wd[p][cc];
            out_d[pg2] = a;
        } else {
            float acc0 = 0.0f, acc1 = 0.0f;
            #pragma unroll
            for (int cc = 0; cc < 8; cc += 2) {
                acc0 += s_w[p][cc]     * vals[u][cc];
                acc1 += s_w[p][cc + 1] * vals[u][cc + 1];
            }
            out_sh[pg2 * NCH + (j - 1)] = acc0 + acc1;
        }
    }
}

extern "C" void kernel_launch(void* const* d_in, const int* in_sizes, int n_in,
                              void* d_out, int out_size, void* d_ws, size_t ws_size,
                              hipStream_t stream) {
    const float* points = (const float*)d_in[0];
    const float* dens   = (const float*)d_in[1];
    const float* sh     = (const float*)d_in[2];
    const int*   links  = (const int*)d_in[3];
    const int n = in_sizes[0] / 3;

    float* out_d  = (float*)d_out;
    float* out_sh = out_d + n;

    const int grid = (n + PTS_PER_BLK - 1) / PTS_PER_BLK;
    hipLaunchKernelGGL(sg_sample_kernel, dim3(grid), dim3(256), 0, stream,
                       points, dens, sh, links, out_d, out_sh, n);
}